// Round 1
// baseline (187.643 us; speedup 1.0000x reference)
//
#include <hip/hip_runtime.h>
#include <hip/hip_bf16.h>

// EdgeWeightFromDistance: out[e] = relu(relu([x[src], y[dst], dist] @ W1 + b1) @ W2 + b2)
// E = 1e6, NODE_DIM = 64, HIDDEN = 128.
// Strategy: bf16 MFMA (16x16x32) for the K=128 part (x|y), dist*W1[128,:] + b1 in fp32,
// second layer fp32 VALU + quad shuffle reduction. A-fragments gathered straight from
// global (8 consecutive floats per lane), B (W1^T) held in registers per wave.

constexpr int NDIM  = 64;
constexpr int HID   = 128;
constexpr int KPAD  = 136;   // LDS K stride (bf16 elems); 272 B row: 16B-aligned b128 reads

typedef __attribute__((ext_vector_type(8))) short  short8;
typedef __attribute__((ext_vector_type(4))) int    int4v;
typedef __attribute__((ext_vector_type(4))) float  floatx4;

__device__ __forceinline__ short f2bf(float f) {
    union { __hip_bfloat16 h; short s; } cv;
    cv.h = __float2bfloat16(f);
    return cv.s;
}

__device__ __forceinline__ int pack2(float a, float b) {
    union { __hip_bfloat162 h; int u; } cv;
    cv.h = __float22bfloat162_rn(float2{a, b});
    return cv.u;
}

__global__ __launch_bounds__(256) void edge_mlp_kernel(
    const float* __restrict__ x, const float* __restrict__ y,
    const int*  __restrict__ ei, const float* __restrict__ px,
    const float* __restrict__ py, const float* __restrict__ W1,
    const float* __restrict__ b1, const float* __restrict__ W2,
    const float* __restrict__ b2, float* __restrict__ out, int E)
{
    __shared__ __align__(16) short Wt[HID * KPAD];   // W1^T [n][k] in bf16

    const int tid = threadIdx.x;

    // ---- stage W1[0:128][0:128] transposed into LDS (one-time per block) ----
    // i = k*128 + n ; coalesced global read, batched 8 loads for latency.
    for (int base = 0; base < HID * HID; base += 256 * 8) {
        float f[8];
#pragma unroll
        for (int u = 0; u < 8; ++u) f[u] = W1[base + u * 256 + tid];
#pragma unroll
        for (int u = 0; u < 8; ++u) {
            int i = base + u * 256 + tid;
            Wt[(i & 127) * KPAD + (i >> 7)] = f2bf(f[u]);
        }
    }
    __syncthreads();

    const int lane = tid & 63;
    const int wave = tid >> 6;
    const int quad = lane >> 4;
    const int lm   = lane & 15;   // A-frag row m; C/D col n (within tile)

    // ---- hoist all B fragments into registers: 8 n-tiles x 4 k-steps ----
    // B[k][n] fragment: n = ntile*16 + lm, k = kstep*32 + quad*8 + j (j=0..7)
    short8 bfrag[8][4];
#pragma unroll
    for (int t = 0; t < 8; ++t) {
        const int n = t * 16 + lm;
#pragma unroll
        for (int s = 0; s < 4; ++s) {
            const int k0 = s * 32 + quad * 8;
            bfrag[t][s] = *reinterpret_cast<const short8*>(&Wt[n * KPAD + k0]);
        }
    }

    // epilogue constants for this lane's n columns (n = t*16 + lm)
    float b1v[8], w2v[8], w1rv[8];
#pragma unroll
    for (int t = 0; t < 8; ++t) {
        const int n = t * 16 + lm;
        b1v[t]  = b1[n];
        w2v[t]  = W2[n];
        w1rv[t] = W1[128 * HID + n];   // last row of W1: the dist coefficient
    }
    const float b2s = b2[0];

    const int* __restrict__ srcp = ei;
    const int* __restrict__ dstp = ei + E;

    const int ntile_cnt = E / 64;   // 64 edges per block-iteration (16 per wave)
    for (int tile = blockIdx.x; tile < ntile_cnt; tile += gridDim.x) {
        const int m_base = tile * 64 + wave * 16;
        int m = m_base + lm;
        if (m >= E) m = E - 1;               // safety clamp (E % 64 == 0 here)
        const int src = srcp[m];
        const int dst = dstp[m];

        // per-edge distance (every lane computes for m = m_base + lm; quads duplicate)
        const float dx = px[src * 3 + 0] - py[dst * 3 + 0];
        const float dy = px[src * 3 + 1] - py[dst * 3 + 1];
        const float dz = px[src * 3 + 2] - py[dst * 3 + 2];
        const float dist = sqrtf(dx * dx + dy * dy + dz * dz);

        // ---- A fragments: row m, k = s*32 + quad*8 + j ; straight from global ----
        short8 afrag[4];
#pragma unroll
        for (int s = 0; s < 4; ++s) {
            const int kk = s * 32 + quad * 8;
            const float* rp = (s < 2) ? (x + src * NDIM + kk)
                                      : (y + dst * NDIM + (kk - 64));
            const floatx4 f0 = *reinterpret_cast<const floatx4*>(rp);
            const floatx4 f1 = *reinterpret_cast<const floatx4*>(rp + 4);
            union { int4v i; short8 s8; } cv;
            cv.i.x = pack2(f0.x, f0.y);
            cv.i.y = pack2(f0.z, f0.w);
            cv.i.z = pack2(f1.x, f1.y);
            cv.i.w = pack2(f1.z, f1.w);
            afrag[s] = cv.s8;
        }

        // ---- MFMA: h[16 edges][128 hidden], fp32 accumulate ----
        floatx4 acc[8];
#pragma unroll
        for (int t = 0; t < 8; ++t) acc[t] = floatx4{0.f, 0.f, 0.f, 0.f};
#pragma unroll
        for (int s = 0; s < 4; ++s) {
#pragma unroll
            for (int t = 0; t < 8; ++t) {
                acc[t] = __builtin_amdgcn_mfma_f32_16x16x32_bf16(
                    afrag[s], bfrag[t][s], acc[t], 0, 0, 0);
            }
        }

        // ---- epilogue: + dist*W1[128,n] + b1, ReLU, dot W2, reduce, +b2, ReLU ----
        // C/D layout: col n = lm (+16t), row m = quad*4 + reg
        const float dm0 = __shfl(dist, quad * 4 + 0, 64);
        const float dm1 = __shfl(dist, quad * 4 + 1, 64);
        const float dm2 = __shfl(dist, quad * 4 + 2, 64);
        const float dm3 = __shfl(dist, quad * 4 + 3, 64);

        float p0 = 0.f, p1 = 0.f, p2 = 0.f, p3 = 0.f;
#pragma unroll
        for (int t = 0; t < 8; ++t) {
            float h;
            h = acc[t][0] + dm0 * w1rv[t] + b1v[t]; h = fmaxf(h, 0.f); p0 += h * w2v[t];
            h = acc[t][1] + dm1 * w1rv[t] + b1v[t]; h = fmaxf(h, 0.f); p1 += h * w2v[t];
            h = acc[t][2] + dm2 * w1rv[t] + b1v[t]; h = fmaxf(h, 0.f); p2 += h * w2v[t];
            h = acc[t][3] + dm3 * w1rv[t] + b1v[t]; h = fmaxf(h, 0.f); p3 += h * w2v[t];
        }
        // sum over the 16 lanes of this quad (covers all 128 n columns)
#pragma unroll
        for (int off = 1; off < 16; off <<= 1) {
            p0 += __shfl_xor(p0, off, 64);
            p1 += __shfl_xor(p1, off, 64);
            p2 += __shfl_xor(p2, off, 64);
            p3 += __shfl_xor(p3, off, 64);
        }
        if (lm < 4) {
            const float v = (lm == 0) ? p0 : (lm == 1) ? p1 : (lm == 2) ? p2 : p3;
            const int e = m_base + quad * 4 + lm;
            if (e < E) out[e] = fmaxf(v + b2s, 0.f);
        }
    }
}

extern "C" void kernel_launch(void* const* d_in, const int* in_sizes, int n_in,
                              void* d_out, int out_size, void* d_ws, size_t ws_size,
                              hipStream_t stream)
{
    const float* x  = (const float*)d_in[0];
    const float* y  = (const float*)d_in[1];
    const int*   ei = (const int*)  d_in[2];
    const float* px = (const float*)d_in[3];
    const float* py = (const float*)d_in[4];
    const float* W1 = (const float*)d_in[5];
    const float* b1 = (const float*)d_in[6];
    const float* W2 = (const float*)d_in[7];
    const float* b2 = (const float*)d_in[8];
    float* out = (float*)d_out;
    const int E = in_sizes[2] / 2;

    edge_mlp_kernel<<<dim3(512), dim3(256), 0, stream>>>(
        x, y, ei, px, py, W1, b1, W2, b2, out, E);
}